// Round 1
// baseline (222.191 us; speedup 1.0000x reference)
//
#include <hip/hip_runtime.h>
#include <math.h>

// GraphGather: segmented mean+max over sorted membership, then tanh.
// atom_features: [N_ATOMS, 128] f32, membership: [N_ATOMS] i32 (sorted, values in [0,BATCH))
// out: [BATCH, 256] f32 = tanh(concat([mean, max], axis=1))

#define D_FEAT 128

__global__ __launch_bounds__(256) void graph_gather_kernel(
    const float* __restrict__ feat,
    const int* __restrict__ mem,
    float* __restrict__ out,
    int n_atoms)
{
    const int b = blockIdx.x;          // segment id
    const int t = threadIdx.x;
    const int c = t & 31;              // float4 column index 0..31 (covers 128 floats)
    const int r = t >> 5;              // row group 0..7

    __shared__ int s_bounds[2];

    // Segment boundaries via binary search (membership is sorted).
    if (t == 0) {
        int lo = 0, hi = n_atoms;
        while (lo < hi) { int mid = (lo + hi) >> 1; if (mem[mid] < b) lo = mid + 1; else hi = mid; }
        s_bounds[0] = lo;
        hi = n_atoms;
        while (lo < hi) { int mid = (lo + hi) >> 1; if (mem[mid] < b + 1) lo = mid + 1; else hi = mid; }
        s_bounds[1] = lo;
    }
    __syncthreads();
    const int start = s_bounds[0];
    const int end   = s_bounds[1];
    const int count = end - start;

    float4 s = make_float4(0.f, 0.f, 0.f, 0.f);
    float4 m = make_float4(-INFINITY, -INFINITY, -INFINITY, -INFINITY);

    const float4* fp = reinterpret_cast<const float4*>(feat);
    for (int row = start + r; row < end; row += 8) {
        float4 v = fp[(size_t)row * (D_FEAT / 4) + c];
        s.x += v.x; s.y += v.y; s.z += v.z; s.w += v.w;
        m.x = fmaxf(m.x, v.x);
        m.y = fmaxf(m.y, v.y);
        m.z = fmaxf(m.z, v.z);
        m.w = fmaxf(m.w, v.w);
    }

    __shared__ float4 ls[256];
    __shared__ float4 lm[256];
    ls[t] = s;
    lm[t] = m;
    __syncthreads();

    if (r == 0) {
        #pragma unroll
        for (int rr = 1; rr < 8; ++rr) {
            float4 s2 = ls[rr * 32 + c];
            float4 m2 = lm[rr * 32 + c];
            s.x += s2.x; s.y += s2.y; s.z += s2.z; s.w += s2.w;
            m.x = fmaxf(m.x, m2.x);
            m.y = fmaxf(m.y, m2.y);
            m.z = fmaxf(m.z, m2.z);
            m.w = fmaxf(m.w, m2.w);
        }
        const float inv = 1.0f / fmaxf((float)count, 1.0f);
        float* ob = out + (size_t)b * (2 * D_FEAT);
        ob[c * 4 + 0] = tanhf(s.x * inv);
        ob[c * 4 + 1] = tanhf(s.y * inv);
        ob[c * 4 + 2] = tanhf(s.z * inv);
        ob[c * 4 + 3] = tanhf(s.w * inv);
        ob[D_FEAT + c * 4 + 0] = tanhf(m.x);
        ob[D_FEAT + c * 4 + 1] = tanhf(m.y);
        ob[D_FEAT + c * 4 + 2] = tanhf(m.z);
        ob[D_FEAT + c * 4 + 3] = tanhf(m.w);
    }
}

extern "C" void kernel_launch(void* const* d_in, const int* in_sizes, int n_in,
                              void* d_out, int out_size, void* d_ws, size_t ws_size,
                              hipStream_t stream) {
    const float* feat = (const float*)d_in[0];
    const int* mem    = (const int*)d_in[1];
    float* out        = (float*)d_out;
    const int n_atoms = in_sizes[1];
    const int batch   = out_size / (2 * D_FEAT);

    graph_gather_kernel<<<batch, 256, 0, stream>>>(feat, mem, out, n_atoms);
}

// Round 2
// 173.867 us; speedup vs baseline: 1.2779x; 1.2779x over previous
//
#include <hip/hip_runtime.h>
#include <math.h>

// GraphGather: segmented mean+max over sorted membership, then tanh.
// atom_features: [N_ATOMS, 128] f32, membership: [N_ATOMS] i32 (sorted, values in [0,BATCH))
// out: [BATCH, 256] f32 = tanh(concat([mean, max], axis=1))

#define D_FEAT 128

typedef float f32x4 __attribute__((ext_vector_type(4)));

__global__ __launch_bounds__(256) void graph_gather_kernel(
    const float* __restrict__ feat,
    const int* __restrict__ mem,
    float* __restrict__ out,
    int n_atoms)
{
    const int b = blockIdx.x;          // segment id
    const int t = threadIdx.x;
    const int c = t & 31;              // float4 column index 0..31 (covers 128 floats)
    const int r = t >> 5;              // row group 0..7

    __shared__ int s_bounds[2];

    // Segment boundaries via binary search (membership is sorted).
    if (t == 0) {
        int lo = 0, hi = n_atoms;
        while (lo < hi) { int mid = (lo + hi) >> 1; if (mem[mid] < b) lo = mid + 1; else hi = mid; }
        s_bounds[0] = lo;
        hi = n_atoms;
        while (lo < hi) { int mid = (lo + hi) >> 1; if (mem[mid] < b + 1) lo = mid + 1; else hi = mid; }
        s_bounds[1] = lo;
    }
    __syncthreads();
    const int start = s_bounds[0];
    const int end   = s_bounds[1];
    const int count = end - start;

    f32x4 s = {0.f, 0.f, 0.f, 0.f};
    f32x4 m = {-INFINITY, -INFINITY, -INFINITY, -INFINITY};

    const f32x4* fp = reinterpret_cast<const f32x4*>(feat);

    // Main loop: 4 independent 16B loads in flight per thread (rows r, r+8, r+16, r+24),
    // stepping 32 rows per iteration. Non-temporal: features are streamed exactly once.
    const int nfull = count & ~31;
    const int main_end = start + nfull;
    for (int row = start + r; row < main_end; row += 32) {
        f32x4 v0 = __builtin_nontemporal_load(&fp[(size_t)(row +  0) * (D_FEAT / 4) + c]);
        f32x4 v1 = __builtin_nontemporal_load(&fp[(size_t)(row +  8) * (D_FEAT / 4) + c]);
        f32x4 v2 = __builtin_nontemporal_load(&fp[(size_t)(row + 16) * (D_FEAT / 4) + c]);
        f32x4 v3 = __builtin_nontemporal_load(&fp[(size_t)(row + 24) * (D_FEAT / 4) + c]);
        s += v0;
        m.x = fmaxf(m.x, v0.x); m.y = fmaxf(m.y, v0.y); m.z = fmaxf(m.z, v0.z); m.w = fmaxf(m.w, v0.w);
        s += v1;
        m.x = fmaxf(m.x, v1.x); m.y = fmaxf(m.y, v1.y); m.z = fmaxf(m.z, v1.z); m.w = fmaxf(m.w, v1.w);
        s += v2;
        m.x = fmaxf(m.x, v2.x); m.y = fmaxf(m.y, v2.y); m.z = fmaxf(m.z, v2.z); m.w = fmaxf(m.w, v2.w);
        s += v3;
        m.x = fmaxf(m.x, v3.x); m.y = fmaxf(m.y, v3.y); m.z = fmaxf(m.z, v3.z); m.w = fmaxf(m.w, v3.w);
    }
    // Remainder rows (count % 32), stride-8 guarded.
    for (int row = main_end + r; row < end; row += 8) {
        f32x4 v = __builtin_nontemporal_load(&fp[(size_t)row * (D_FEAT / 4) + c]);
        s += v;
        m.x = fmaxf(m.x, v.x); m.y = fmaxf(m.y, v.y); m.z = fmaxf(m.z, v.z); m.w = fmaxf(m.w, v.w);
    }

    __shared__ f32x4 ls[256];
    __shared__ f32x4 lm[256];
    ls[t] = s;
    lm[t] = m;
    __syncthreads();

    if (r == 0) {
        #pragma unroll
        for (int rr = 1; rr < 8; ++rr) {
            f32x4 s2 = ls[rr * 32 + c];
            f32x4 m2 = lm[rr * 32 + c];
            s += s2;
            m.x = fmaxf(m.x, m2.x); m.y = fmaxf(m.y, m2.y); m.z = fmaxf(m.z, m2.z); m.w = fmaxf(m.w, m2.w);
        }
        const float inv = 1.0f / fmaxf((float)count, 1.0f);
        float* ob = out + (size_t)b * (2 * D_FEAT);
        ob[c * 4 + 0] = tanhf(s.x * inv);
        ob[c * 4 + 1] = tanhf(s.y * inv);
        ob[c * 4 + 2] = tanhf(s.z * inv);
        ob[c * 4 + 3] = tanhf(s.w * inv);
        ob[D_FEAT + c * 4 + 0] = tanhf(m.x);
        ob[D_FEAT + c * 4 + 1] = tanhf(m.y);
        ob[D_FEAT + c * 4 + 2] = tanhf(m.z);
        ob[D_FEAT + c * 4 + 3] = tanhf(m.w);
    }
}

extern "C" void kernel_launch(void* const* d_in, const int* in_sizes, int n_in,
                              void* d_out, int out_size, void* d_ws, size_t ws_size,
                              hipStream_t stream) {
    const float* feat = (const float*)d_in[0];
    const int* mem    = (const int*)d_in[1];
    float* out        = (float*)d_out;
    const int n_atoms = in_sizes[1];
    const int batch   = out_size / (2 * D_FEAT);

    graph_gather_kernel<<<batch, 256, 0, stream>>>(feat, mem, out, n_atoms);
}